// Round 4
// baseline (46.852 us; speedup 1.0000x reference)
//
#include <hip/hip_runtime.h>

#define NT 64    // ONE WAVE per workgroup -> zero __syncthreads
#define NJ 22

struct X9 { float r[9]; float t[3]; };

__device__ __forceinline__ void rodrigues(float ax, float ay, float az, float* R) {
    float sq   = ax*ax + ay*ay + az*az + 1e-12f;
    float rinv = rsqrtf(sq);
    float ang  = sq * rinv;          // sqrt(sq)
    float s, c;
    __sincosf(ang, &s, &c);
    float x = ax*rinv, y = ay*rinv, z = az*rinv;
    float t = 1.0f - c;
    R[0] = t*x*x + c;   R[1] = t*x*y - s*z; R[2] = t*x*z + s*y;
    R[3] = t*x*y + s*z; R[4] = t*y*y + c;   R[5] = t*y*z - s*x;
    R[6] = t*x*z - s*y; R[7] = t*y*z + s*x; R[8] = t*z*z + c;
}

// local[j] = LT[j] + sum_k betas[k]*LDpad[j][k], rows padded to 12 floats (3x float4)
__device__ __forceinline__ void local_pos(int j, const float* bt,
                                          const float* LT, const float4* LD4,
                                          float* lt) {
    #pragma unroll
    for (int c = 0; c < 3; ++c) {
        float v = LT[j*3 + c];
        const float4 a0 = LD4[(j*3 + c)*3 + 0];
        const float4 a1 = LD4[(j*3 + c)*3 + 1];
        const float4 a2 = LD4[(j*3 + c)*3 + 2];
        v = fmaf(bt[0], a0.x, v); v = fmaf(bt[1], a0.y, v);
        v = fmaf(bt[2], a0.z, v); v = fmaf(bt[3], a0.w, v);
        v = fmaf(bt[4], a1.x, v); v = fmaf(bt[5], a1.y, v);
        v = fmaf(bt[6], a1.z, v); v = fmaf(bt[7], a1.w, v);
        v = fmaf(bt[8], a2.x, v); v = fmaf(bt[9], a2.y, v);
        lt[c] = v;
    }
}

// aa in registers; writes joint position into s_o[J*3..]
template<int J>
__device__ __forceinline__ X9 step(const X9& gp, const float* aa, const float* bt,
                                   const float* LT, const float4* LD4, float* s_o) {
    float R[9];
    rodrigues(aa[(J-1)*3 + 0], aa[(J-1)*3 + 1], aa[(J-1)*3 + 2], R);
    float lt[3];
    local_pos(J, bt, LT, LD4, lt);
    X9 g;
    #pragma unroll
    for (int r = 0; r < 3; ++r) {
        #pragma unroll
        for (int c = 0; c < 3; ++c)
            g.r[r*3+c] = fmaf(gp.r[r*3+0], R[c],
                         fmaf(gp.r[r*3+1], R[3+c],
                              gp.r[r*3+2] * R[6+c]));
        g.t[r] = fmaf(gp.r[r*3+0], lt[0],
                 fmaf(gp.r[r*3+1], lt[1],
                 fmaf(gp.r[r*3+2], lt[2], gp.t[r])));
    }
    s_o[J*3+0] = g.t[0]; s_o[J*3+1] = g.t[1]; s_o[J*3+2] = g.t[2];
    return g;
}

__global__ __launch_bounds__(NT, 2) void fk_joints_kernel(
    const float* __restrict__ body_pose,     // (S,63)
    const float* __restrict__ betas,         // (S,10)
    const float* __restrict__ global_orient, // (S,3)
    const float* __restrict__ transl,        // (S,3)
    const float* __restrict__ J_template,    // (22,3)
    const float* __restrict__ J_shapedirs,   // (22,3,10)
    float* __restrict__ out)                 // (S,22,3)
{
    // One wave per block: DS pipe is in-order per wave -> no barriers anywhere.
    __shared__ float  s_buf[NT*66];          // bp transpose (NT*63 used) -> output gather
    __shared__ float  s_small[NT*16];        // [0,640) betas | [640,832) go | [832,1024) tr
    __shared__ float  s_LT[NJ*3];
    __shared__ float4 s_LD4[NJ*3*3];         // 66 rows x 12 floats (2 pad)

    const int tid = threadIdx.x;
    const long long s0 = (long long)blockIdx.x * NT;

    // ---- stage all inputs (coalesced float4), build tables; no barriers ----
    {
        const float4* src = reinterpret_cast<const float4*>(body_pose + s0*63);
        float4* dst = reinterpret_cast<float4*>(s_buf);
        for (int i = tid; i < NT*63/4; i += NT) dst[i] = src[i];   // 1008 f4
    }
    {
        const float4* src = reinterpret_cast<const float4*>(betas + s0*10);
        float4* dst = reinterpret_cast<float4*>(s_small);
        for (int i = tid; i < NT*10/4; i += NT) dst[i] = src[i];   // 160 f4
    }
    {
        const float4* src = reinterpret_cast<const float4*>(global_orient + s0*3);
        float4* dst = reinterpret_cast<float4*>(s_small + NT*10);
        if (tid < NT*3/4) dst[tid] = src[tid];                     // 48 f4
    }
    {
        const float4* src = reinterpret_cast<const float4*>(transl + s0*3);
        float4* dst = reinterpret_cast<float4*>(s_small + NT*13);
        if (tid < NT*3/4) dst[tid] = src[tid];                     // 48 f4
    }
    const int P[NJ] = {0,0,0,0,1,2,3,4,5,6,7,8,9,9,9,12,13,14,16,17,18,19};
    float* s_LD = reinterpret_cast<float*>(s_LD4);
    for (int i = tid; i < NJ*3; i += NT) {
        int j = i/3, c = i - j*3;
        float v = J_template[i];
        if (j) v -= J_template[P[j]*3 + c];
        s_LT[i] = v;
        s_LD[i*12 + 10] = 0.0f;
        s_LD[i*12 + 11] = 0.0f;
    }
    for (int i = tid; i < NJ*30; i += NT) {
        int jc = i/10, k = i - jc*10;
        int j = jc/3,  c = jc - j*3;
        float v = J_shapedirs[i];
        if (j) v -= J_shapedirs[(P[j]*3 + c)*10 + k];
        s_LD[jc*12 + k] = v;
    }
    __builtin_amdgcn_wave_barrier();   // compiler fence only; DS is in-order per wave

    // ---- transpose reads: per-sample data -> registers ----
    float aa[63];
    #pragma unroll
    for (int k = 0; k < 63; ++k) aa[k] = s_buf[tid*63 + k];   // stride 63: 2-way, free
    float bt[10];
    #pragma unroll
    for (int k = 0; k < 10; ++k) bt[k] = s_small[tid*10 + k];
    const float gox = s_small[NT*10 + tid*3 + 0];
    const float goy = s_small[NT*10 + tid*3 + 1];
    const float goz = s_small[NT*10 + tid*3 + 2];
    const float trx = s_small[NT*13 + tid*3 + 0];
    const float try_ = s_small[NT*13 + tid*3 + 1];
    const float trz = s_small[NT*13 + tid*3 + 2];
    __builtin_amdgcn_wave_barrier();

    // ---- FK fully in registers; joint positions -> s_buf[tid*66 + ...] ----
    float* s_o = &s_buf[tid*66];

    X9 g0;
    rodrigues(gox, goy, goz, g0.r);
    {
        float lt0[3];
        local_pos(0, bt, s_LT, s_LD4, lt0);
        g0.t[0] = lt0[0] + trx;
        g0.t[1] = lt0[1] + try_;
        g0.t[2] = lt0[2] + trz;
        s_o[0] = g0.t[0]; s_o[1] = g0.t[1]; s_o[2] = g0.t[2];
    }

    X9 g;
    // chain A: 0 -> 1 -> 4 -> 7 -> 10
    g = step<1 >(g0, aa, bt, s_LT, s_LD4, s_o);
    g = step<4 >(g,  aa, bt, s_LT, s_LD4, s_o);
    g = step<7 >(g,  aa, bt, s_LT, s_LD4, s_o);
    g = step<10>(g,  aa, bt, s_LT, s_LD4, s_o);
    // chain B: 0 -> 2 -> 5 -> 8 -> 11
    g = step<2 >(g0, aa, bt, s_LT, s_LD4, s_o);
    g = step<5 >(g,  aa, bt, s_LT, s_LD4, s_o);
    g = step<8 >(g,  aa, bt, s_LT, s_LD4, s_o);
    g = step<11>(g,  aa, bt, s_LT, s_LD4, s_o);
    // chain C: 0 -> 3 -> 6 -> 9
    g = step<3 >(g0, aa, bt, s_LT, s_LD4, s_o);
    g = step<6 >(g,  aa, bt, s_LT, s_LD4, s_o);
    X9 g9 = step<9>(g, aa, bt, s_LT, s_LD4, s_o);
    // chain D: 9 -> 12 -> 15
    g = step<12>(g9, aa, bt, s_LT, s_LD4, s_o);
    g = step<15>(g,  aa, bt, s_LT, s_LD4, s_o);
    // chain E: 9 -> 13 -> 16 -> 18 -> 20
    g = step<13>(g9, aa, bt, s_LT, s_LD4, s_o);
    g = step<16>(g,  aa, bt, s_LT, s_LD4, s_o);
    g = step<18>(g,  aa, bt, s_LT, s_LD4, s_o);
    g = step<20>(g,  aa, bt, s_LT, s_LD4, s_o);
    // chain F: 9 -> 14 -> 17 -> 19 -> 21
    g = step<14>(g9, aa, bt, s_LT, s_LD4, s_o);
    g = step<17>(g,  aa, bt, s_LT, s_LD4, s_o);
    g = step<19>(g,  aa, bt, s_LT, s_LD4, s_o);
    g = step<21>(g,  aa, bt, s_LT, s_LD4, s_o);

    __builtin_amdgcn_wave_barrier();

    // ---- pure float4 copy LDS -> global (coalesced, conflict-free) ----
    {
        const float4* src = reinterpret_cast<const float4*>(s_buf);
        float4* dst = reinterpret_cast<float4*>(out + s0 * (NJ*3));
        for (int i = tid; i < NT*NJ*3/4; i += NT) dst[i] = src[i];   // 1056 f4
    }
}

extern "C" void kernel_launch(void* const* d_in, const int* in_sizes, int n_in,
                              void* d_out, int out_size, void* d_ws, size_t ws_size,
                              hipStream_t stream) {
    const float* body_pose     = (const float*)d_in[0];
    const float* betas         = (const float*)d_in[1];
    const float* global_orient = (const float*)d_in[2];
    const float* transl        = (const float*)d_in[3];
    const float* J_template    = (const float*)d_in[4];
    const float* J_shapedirs   = (const float*)d_in[5];
    float* out = (float*)d_out;

    const int S = in_sizes[0] / 63;        // B*L = 131072 (divisible by NT)
    const int blocks = S / NT;

    hipLaunchKernelGGL(fk_joints_kernel, dim3(blocks), dim3(NT), 0, stream,
                       body_pose, betas, global_orient, transl,
                       J_template, J_shapedirs, out);
}

// Round 5
// 32.104 us; speedup vs baseline: 1.4594x; 1.4594x over previous
//
#include <hip/hip_runtime.h>

#define NT  128  // 2 waves/block; waves are fully independent (zero __syncthreads)
#define WSZ 64
#define NJ  22

struct X9 { float r[9]; float t[3]; };

__device__ __forceinline__ void rodrigues(float ax, float ay, float az, float* R) {
    float sq   = ax*ax + ay*ay + az*az + 1e-12f;
    float rinv = rsqrtf(sq);
    float ang  = sq * rinv;          // sqrt(sq)
    float s, c;
    __sincosf(ang, &s, &c);
    float x = ax*rinv, y = ay*rinv, z = az*rinv;
    float t = 1.0f - c;
    R[0] = t*x*x + c;   R[1] = t*x*y - s*z; R[2] = t*x*z + s*y;
    R[3] = t*x*y + s*z; R[4] = t*y*y + c;   R[5] = t*y*z - s*x;
    R[6] = t*x*z - s*y; R[7] = t*y*z + s*x; R[8] = t*z*z + c;
}

// local[j] = LT[j] + sum_k betas[k]*LDpad[j][k], rows padded to 12 floats (3x float4)
__device__ __forceinline__ void local_pos(int j, const float* bt,
                                          const float* LT, const float4* LD4,
                                          float* lt) {
    #pragma unroll
    for (int c = 0; c < 3; ++c) {
        float v = LT[j*3 + c];
        const float4 a0 = LD4[(j*3 + c)*3 + 0];
        const float4 a1 = LD4[(j*3 + c)*3 + 1];
        const float4 a2 = LD4[(j*3 + c)*3 + 2];
        v = fmaf(bt[0], a0.x, v); v = fmaf(bt[1], a0.y, v);
        v = fmaf(bt[2], a0.z, v); v = fmaf(bt[3], a0.w, v);
        v = fmaf(bt[4], a1.x, v); v = fmaf(bt[5], a1.y, v);
        v = fmaf(bt[6], a1.z, v); v = fmaf(bt[7], a1.w, v);
        v = fmaf(bt[8], a2.x, v); v = fmaf(bt[9], a2.y, v);
        lt[c] = v;
    }
}

// aa in registers; writes joint position into s_o[J*3..]
template<int J>
__device__ __forceinline__ X9 step(const X9& gp, const float* aa, const float* bt,
                                   const float* LT, const float4* LD4, float* s_o) {
    float R[9];
    rodrigues(aa[(J-1)*3 + 0], aa[(J-1)*3 + 1], aa[(J-1)*3 + 2], R);
    float lt[3];
    local_pos(J, bt, LT, LD4, lt);
    X9 g;
    #pragma unroll
    for (int r = 0; r < 3; ++r) {
        #pragma unroll
        for (int c = 0; c < 3; ++c)
            g.r[r*3+c] = fmaf(gp.r[r*3+0], R[c],
                         fmaf(gp.r[r*3+1], R[3+c],
                              gp.r[r*3+2] * R[6+c]));
        g.t[r] = fmaf(gp.r[r*3+0], lt[0],
                 fmaf(gp.r[r*3+1], lt[1],
                 fmaf(gp.r[r*3+2], lt[2], gp.t[r])));
    }
    s_o[J*3+0] = g.t[0]; s_o[J*3+1] = g.t[1]; s_o[J*3+2] = g.t[2];
    return g;
}

__global__ __launch_bounds__(NT, 2) void fk_joints_kernel(
    const float* __restrict__ body_pose,     // (S,63)
    const float* __restrict__ betas,         // (S,10)
    const float* __restrict__ global_orient, // (S,3)
    const float* __restrict__ transl,        // (S,3)
    const float* __restrict__ J_template,    // (22,3)
    const float* __restrict__ J_shapedirs,   // (22,3,10)
    float* __restrict__ out)                 // (S,22,3)
{
    // Wave-private regions (64 samples x 66 floats): bp staged at the region
    // head (64x63), FK outputs later overlay the same region (64x66).
    // Intra-wave DS ordering is guaranteed by the in-order DS pipe + fences.
    __shared__ float  s_buf[NT*66];          // 33792 B
    __shared__ float  s_LT[NJ*3];
    __shared__ float4 s_LD4[NJ*3*3];         // 66 rows x 12 floats (2 pad)

    const int  tid  = threadIdx.x;
    const int  lane = tid & (WSZ-1);
    const int  wid  = tid >> 6;
    const long long sw = (long long)blockIdx.x * NT + (long long)wid * WSZ; // wave's 1st sample
    const long long s  = sw + lane;                                         // this lane's sample

    // ---- direct per-lane loads of small inputs (issue first, fill under staging) ----
    const float gox = global_orient[s*3 + 0];
    const float goy = global_orient[s*3 + 1];
    const float goz = global_orient[s*3 + 2];
    const float trx = transl[s*3 + 0];
    const float try_ = transl[s*3 + 1];
    const float trz = transl[s*3 + 2];
    float bt[10];
    {
        const float2* b2 = reinterpret_cast<const float2*>(betas + s*10); // 40B stride: 8B aligned
        #pragma unroll
        for (int k = 0; k < 5; ++k) {
            float2 v = b2[k];
            bt[2*k+0] = v.x; bt[2*k+1] = v.y;
        }
    }

    // ---- stage OWN wave's body_pose chunk (coalesced float4), wave-private ----
    float* myb = s_buf + wid * (WSZ*66);
    {
        const float4* src = reinterpret_cast<const float4*>(body_pose + sw*63);
        float4* dst = reinterpret_cast<float4*>(myb);
        #pragma unroll
        for (int i = lane; i < WSZ*63/4; i += WSZ) dst[i] = src[i];   // 1008 f4, 16 iters
    }

    // ---- tables: EACH wave writes the full tables (identical values -> benign dup) ----
    const int P[NJ] = {0,0,0,0,1,2,3,4,5,6,7,8,9,9,9,12,13,14,16,17,18,19};
    float* s_LD = reinterpret_cast<float*>(s_LD4);
    for (int i = lane; i < NJ*3; i += WSZ) {
        int j = i/3, c = i - j*3;
        float v = J_template[i];
        if (j) v -= J_template[P[j]*3 + c];
        s_LT[i] = v;
        s_LD[i*12 + 10] = 0.0f;
        s_LD[i*12 + 11] = 0.0f;
    }
    for (int i = lane; i < NJ*30; i += WSZ) {
        int jc = i/10, k = i - jc*10;
        int j = jc/3,  c = jc - j*3;
        float v = J_shapedirs[i];
        if (j) v -= J_shapedirs[(P[j]*3 + c)*10 + k];
        s_LD[jc*12 + k] = v;
    }
    __builtin_amdgcn_wave_barrier();   // fence: staging ds_writes before transpose ds_reads

    // ---- transpose read: own sample's 63 pose floats -> registers (stride 63: 2-way, free) ----
    float aa[63];
    #pragma unroll
    for (int k = 0; k < 63; ++k) aa[k] = myb[lane*63 + k];
    __builtin_amdgcn_wave_barrier();   // fence: transpose reads before FK output writes

    // ---- FK fully in registers; joint positions -> myb[lane*66 + ...] ----
    float* s_o = myb + lane*66;

    X9 g0;
    rodrigues(gox, goy, goz, g0.r);
    {
        float lt0[3];
        local_pos(0, bt, s_LT, s_LD4, lt0);
        g0.t[0] = lt0[0] + trx;
        g0.t[1] = lt0[1] + try_;
        g0.t[2] = lt0[2] + trz;
        s_o[0] = g0.t[0]; s_o[1] = g0.t[1]; s_o[2] = g0.t[2];
    }

    X9 g;
    // chain A: 0 -> 1 -> 4 -> 7 -> 10
    g = step<1 >(g0, aa, bt, s_LT, s_LD4, s_o);
    g = step<4 >(g,  aa, bt, s_LT, s_LD4, s_o);
    g = step<7 >(g,  aa, bt, s_LT, s_LD4, s_o);
    g = step<10>(g,  aa, bt, s_LT, s_LD4, s_o);
    // chain B: 0 -> 2 -> 5 -> 8 -> 11
    g = step<2 >(g0, aa, bt, s_LT, s_LD4, s_o);
    g = step<5 >(g,  aa, bt, s_LT, s_LD4, s_o);
    g = step<8 >(g,  aa, bt, s_LT, s_LD4, s_o);
    g = step<11>(g,  aa, bt, s_LT, s_LD4, s_o);
    // chain C: 0 -> 3 -> 6 -> 9
    g = step<3 >(g0, aa, bt, s_LT, s_LD4, s_o);
    g = step<6 >(g,  aa, bt, s_LT, s_LD4, s_o);
    X9 g9 = step<9>(g, aa, bt, s_LT, s_LD4, s_o);
    // chain D: 9 -> 12 -> 15
    g = step<12>(g9, aa, bt, s_LT, s_LD4, s_o);
    g = step<15>(g,  aa, bt, s_LT, s_LD4, s_o);
    // chain E: 9 -> 13 -> 16 -> 18 -> 20
    g = step<13>(g9, aa, bt, s_LT, s_LD4, s_o);
    g = step<16>(g,  aa, bt, s_LT, s_LD4, s_o);
    g = step<18>(g,  aa, bt, s_LT, s_LD4, s_o);
    g = step<20>(g,  aa, bt, s_LT, s_LD4, s_o);
    // chain F: 9 -> 14 -> 17 -> 19 -> 21
    g = step<14>(g9, aa, bt, s_LT, s_LD4, s_o);
    g = step<17>(g,  aa, bt, s_LT, s_LD4, s_o);
    g = step<19>(g,  aa, bt, s_LT, s_LD4, s_o);
    g = step<21>(g,  aa, bt, s_LT, s_LD4, s_o);

    __builtin_amdgcn_wave_barrier();   // fence: FK ds_writes before gather ds_reads

    // ---- coalesced float4 copy of OWN wave's output region (no cross-wave data) ----
    {
        const float4* src = reinterpret_cast<const float4*>(myb);
        float4* dst = reinterpret_cast<float4*>(out + sw * (NJ*3));
        #pragma unroll
        for (int i = lane; i < WSZ*66/4; i += WSZ) dst[i] = src[i];   // 1056 f4, 17 iters
    }
}

extern "C" void kernel_launch(void* const* d_in, const int* in_sizes, int n_in,
                              void* d_out, int out_size, void* d_ws, size_t ws_size,
                              hipStream_t stream) {
    const float* body_pose     = (const float*)d_in[0];
    const float* betas         = (const float*)d_in[1];
    const float* global_orient = (const float*)d_in[2];
    const float* transl        = (const float*)d_in[3];
    const float* J_template    = (const float*)d_in[4];
    const float* J_shapedirs   = (const float*)d_in[5];
    float* out = (float*)d_out;

    const int S = in_sizes[0] / 63;        // B*L = 131072 (divisible by NT)
    const int blocks = S / NT;

    hipLaunchKernelGGL(fk_joints_kernel, dim3(blocks), dim3(NT), 0, stream,
                       body_pose, betas, global_orient, transl,
                       J_template, J_shapedirs, out);
}

// Round 6
// 31.358 us; speedup vs baseline: 1.4941x; 1.0238x over previous
//
#include <hip/hip_runtime.h>

#define NT  128  // 2 waves/block; waves fully independent (zero __syncthreads)
#define WSZ 64
#define NJ  22

struct X9 { float r[9]; float t[3]; };

__device__ __forceinline__ void rodrigues(float ax, float ay, float az, float* R) {
    float sq   = ax*ax + ay*ay + az*az + 1e-12f;
    float rinv = rsqrtf(sq);
    float ang  = sq * rinv;          // sqrt(sq)
    float s, c;
    __sincosf(ang, &s, &c);
    float x = ax*rinv, y = ay*rinv, z = az*rinv;
    float t = 1.0f - c;
    R[0] = t*x*x + c;   R[1] = t*x*y - s*z; R[2] = t*x*z + s*y;
    R[3] = t*x*y + s*z; R[4] = t*y*y + c;   R[5] = t*y*z - s*x;
    R[6] = t*x*z - s*y; R[7] = t*y*z + s*x; R[8] = t*z*z + c;
}

// Row layout (12 floats): [d0..d9, LT, 0].  local = LT + sum_k bt[k]*d[k]
__device__ __forceinline__ void local_pos(int j, const float* bt,
                                          const float4* LD4, float* lt) {
    #pragma unroll
    for (int c = 0; c < 3; ++c) {
        const float4 a0 = LD4[(j*3 + c)*3 + 0];
        const float4 a1 = LD4[(j*3 + c)*3 + 1];
        const float4 a2 = LD4[(j*3 + c)*3 + 2];
        float v = a2.z;                                  // LT folded into pad slot
        v = fmaf(bt[0], a0.x, v); v = fmaf(bt[1], a0.y, v);
        v = fmaf(bt[2], a0.z, v); v = fmaf(bt[3], a0.w, v);
        v = fmaf(bt[4], a1.x, v); v = fmaf(bt[5], a1.y, v);
        v = fmaf(bt[6], a1.z, v); v = fmaf(bt[7], a1.w, v);
        v = fmaf(bt[8], a2.x, v); v = fmaf(bt[9], a2.y, v);
        lt[c] = v;
    }
}

template<int J>
__device__ __forceinline__ X9 step(const X9& gp, const float* aa, const float* bt,
                                   const float4* LD4, float* s_o) {
    float R[9];
    rodrigues(aa[(J-1)*3 + 0], aa[(J-1)*3 + 1], aa[(J-1)*3 + 2], R);
    float lt[3];
    local_pos(J, bt, LD4, lt);
    X9 g;
    #pragma unroll
    for (int r = 0; r < 3; ++r) {
        #pragma unroll
        for (int c = 0; c < 3; ++c)
            g.r[r*3+c] = fmaf(gp.r[r*3+0], R[c],
                         fmaf(gp.r[r*3+1], R[3+c],
                              gp.r[r*3+2] * R[6+c]));
        g.t[r] = fmaf(gp.r[r*3+0], lt[0],
                 fmaf(gp.r[r*3+1], lt[1],
                 fmaf(gp.r[r*3+2], lt[2], gp.t[r])));
    }
    s_o[J*3+0] = g.t[0]; s_o[J*3+1] = g.t[1]; s_o[J*3+2] = g.t[2];
    return g;
}

__global__ __launch_bounds__(NT)
__attribute__((amdgpu_waves_per_eu(2, 2)))   // exactly 2 waves/SIMD (= grid's structural cap)
void fk_joints_kernel(                        // -> VGPR budget 256, no scratch spill
    const float* __restrict__ body_pose,     // (S,63)
    const float* __restrict__ betas,         // (S,10)
    const float* __restrict__ global_orient, // (S,3)
    const float* __restrict__ transl,        // (S,3)
    const float* __restrict__ J_template,    // (22,3)
    const float* __restrict__ J_shapedirs,   // (22,3,10)
    float* __restrict__ out)                 // (S,22,3)
{
    // Wave-private regions (64 samples x 66 floats): pose staged at region head
    // (64x63), FK outputs later overlay the same region (64x66). Intra-wave DS
    // ordering guaranteed by the in-order DS pipe + compiler fences.
    __shared__ float  s_buf[NT*66];          // 33792 B
    __shared__ float4 s_LD4[NJ*3*3];         // 66 rows x 12 floats: [dirs(10), LT, 0]

    const int  tid  = threadIdx.x;
    const int  lane = tid & (WSZ-1);
    const int  wid  = tid >> 6;
    const long long sw = (long long)blockIdx.x * NT + (long long)wid * WSZ;
    const long long s  = sw + lane;

    // ---- direct per-lane loads of small inputs (latency hides under staging) ----
    const float gox = global_orient[s*3 + 0];
    const float goy = global_orient[s*3 + 1];
    const float goz = global_orient[s*3 + 2];
    const float trx = transl[s*3 + 0];
    const float try_ = transl[s*3 + 1];
    const float trz = transl[s*3 + 2];
    float bt[10];
    {
        const float2* b2 = reinterpret_cast<const float2*>(betas + s*10);
        #pragma unroll
        for (int k = 0; k < 5; ++k) {
            float2 v = b2[k];
            bt[2*k+0] = v.x; bt[2*k+1] = v.y;
        }
    }

    // ---- stage OWN wave's body_pose chunk (coalesced float4), wave-private ----
    float* myb = s_buf + wid * (WSZ*66);
    {
        const float4* src = reinterpret_cast<const float4*>(body_pose + sw*63);
        float4* dst = reinterpret_cast<float4*>(myb);
        #pragma unroll
        for (int i = lane; i < WSZ*63/4; i += WSZ) dst[i] = src[i];   // 1008 f4
    }

    // ---- tables: EACH wave writes identical values (benign duplicate) ----
    const int P[NJ] = {0,0,0,0,1,2,3,4,5,6,7,8,9,9,9,12,13,14,16,17,18,19};
    float* s_LD = reinterpret_cast<float*>(s_LD4);
    for (int i = lane; i < NJ*3; i += WSZ) {
        int j = i/3, c = i - j*3;
        float v = J_template[i];
        if (j) v -= J_template[P[j]*3 + c];
        s_LD[i*12 + 10] = v;       // LT in pad slot
        s_LD[i*12 + 11] = 0.0f;
    }
    for (int i = lane; i < NJ*30; i += WSZ) {
        int jc = i/10, k = i - jc*10;
        int j = jc/3,  c = jc - j*3;
        float v = J_shapedirs[i];
        if (j) v -= J_shapedirs[(P[j]*3 + c)*10 + k];
        s_LD[jc*12 + k] = v;
    }
    __builtin_amdgcn_wave_barrier();   // fence: staging writes before transpose reads

    // ---- transpose read: own 63 pose floats -> registers (stride 63, conflict-free) ----
    float aa[63];
    #pragma unroll
    for (int k = 0; k < 63; ++k) aa[k] = myb[lane*63 + k];
    __builtin_amdgcn_wave_barrier();   // fence: transpose reads before FK output writes

    // ---- FK fully in registers; joint positions -> myb[lane*66 + ...] ----
    float* s_o = myb + lane*66;

    X9 g0;
    rodrigues(gox, goy, goz, g0.r);
    {
        float lt0[3];
        local_pos(0, bt, s_LD4, lt0);
        g0.t[0] = lt0[0] + trx;
        g0.t[1] = lt0[1] + try_;
        g0.t[2] = lt0[2] + trz;
        s_o[0] = g0.t[0]; s_o[1] = g0.t[1]; s_o[2] = g0.t[2];
    }

    X9 g;
    // chain A: 0 -> 1 -> 4 -> 7 -> 10
    g = step<1 >(g0, aa, bt, s_LD4, s_o);
    g = step<4 >(g,  aa, bt, s_LD4, s_o);
    g = step<7 >(g,  aa, bt, s_LD4, s_o);
    g = step<10>(g,  aa, bt, s_LD4, s_o);
    // chain B: 0 -> 2 -> 5 -> 8 -> 11
    g = step<2 >(g0, aa, bt, s_LD4, s_o);
    g = step<5 >(g,  aa, bt, s_LD4, s_o);
    g = step<8 >(g,  aa, bt, s_LD4, s_o);
    g = step<11>(g,  aa, bt, s_LD4, s_o);
    // chain C: 0 -> 3 -> 6 -> 9
    g = step<3 >(g0, aa, bt, s_LD4, s_o);
    g = step<6 >(g,  aa, bt, s_LD4, s_o);
    X9 g9 = step<9>(g, aa, bt, s_LD4, s_o);
    // chain D: 9 -> 12 -> 15
    g = step<12>(g9, aa, bt, s_LD4, s_o);
    g = step<15>(g,  aa, bt, s_LD4, s_o);
    // chain E: 9 -> 13 -> 16 -> 18 -> 20
    g = step<13>(g9, aa, bt, s_LD4, s_o);
    g = step<16>(g,  aa, bt, s_LD4, s_o);
    g = step<18>(g,  aa, bt, s_LD4, s_o);
    g = step<20>(g,  aa, bt, s_LD4, s_o);
    // chain F: 9 -> 14 -> 17 -> 19 -> 21
    g = step<14>(g9, aa, bt, s_LD4, s_o);
    g = step<17>(g,  aa, bt, s_LD4, s_o);
    g = step<19>(g,  aa, bt, s_LD4, s_o);
    g = step<21>(g,  aa, bt, s_LD4, s_o);

    __builtin_amdgcn_wave_barrier();   // fence: FK writes before gather reads

    // ---- coalesced float4 copy of OWN wave's output region ----
    {
        const float4* src = reinterpret_cast<const float4*>(myb);
        float4* dst = reinterpret_cast<float4*>(out + sw * (NJ*3));
        #pragma unroll
        for (int i = lane; i < WSZ*66/4; i += WSZ) dst[i] = src[i];   // 1056 f4
    }
}

extern "C" void kernel_launch(void* const* d_in, const int* in_sizes, int n_in,
                              void* d_out, int out_size, void* d_ws, size_t ws_size,
                              hipStream_t stream) {
    const float* body_pose     = (const float*)d_in[0];
    const float* betas         = (const float*)d_in[1];
    const float* global_orient = (const float*)d_in[2];
    const float* transl        = (const float*)d_in[3];
    const float* J_template    = (const float*)d_in[4];
    const float* J_shapedirs   = (const float*)d_in[5];
    float* out = (float*)d_out;

    const int S = in_sizes[0] / 63;        // B*L = 131072 (divisible by NT)
    const int blocks = S / NT;

    hipLaunchKernelGGL(fk_joints_kernel, dim3(blocks), dim3(NT), 0, stream,
                       body_pose, betas, global_orient, transl,
                       J_template, J_shapedirs, out);
}